// Round 4
// baseline (202.400 us; speedup 1.0000x reference)
//
#include <hip/hip_runtime.h>
#include <math.h>

// RandomMicEQ: cascade of 3 biquads (EQ -> LP -> HP), stage outputs clamped
// to [-1,1], recursion history UNCLAMPED (matches jax ref).
//
// Overlap-save chunking: thread = one L=128-sample chunk, run from zero state
// W=256 samples early (dominant pole r=0.9702 -> transient ~1.3e-4, well
// under the 7.7e-3 threshold; measured absmax 1.95e-3 is fp32 roundoff).
//
// R4: stage the INPUT tile in LDS too. R3 fixed write RMW (WRITE 164->60MB)
// but reads were still 64-line-divergent per wave load: ~64 TA cycles/load +
// full-line L2->L1 transfers with no reuse (L1 reuse distance 154KB >> 32KB)
// -> ~4-8x L2-side amplification, 85% VALU stall. Now: block loads its
// 8448-sample span coalesced into LDS (pad 1 float4 per 32 -> lane stride
// 132 dwords == 4 mod 32 -> even minimum bank load for b128), compute reads
// ds_read_b128, output staged per 32-sample piece (pitch 36) and flushed as
// full 128B lines. HBM traffic ~= ideal: 58MB fetch + 57MB write.

struct BQ { float b0, b1, b2, a1, a2; };

#define L_CHUNK   128
#define W_WARM    256
#define NCH       64                        // chunks per block (= lanes)
#define SPAN      (NCH * L_CHUNK)           // 8192 samples per block span
#define TILE_F    (SPAN + W_WARM)           // 8448 floats max
#define TILE_ROWS ((TILE_F + 127) / 128)    // 66
#define TILE_V4   (TILE_ROWS * 33)          // 2178 float4 (32 data + 1 pad)
#define PIECE     32
#define NPIECE    (L_CHUNK / PIECE)         // 4
#define OP4       9                         // out-staging pitch: 9 float4 = 36 dwords

__global__ __launch_bounds__(64) void biquad3_kernel(
    const float* __restrict__ x, float* __restrict__ out,
    int T, int chunksPerRow, BQ F1, BQ F2, BQ F3)
{
    __shared__ float4 tile4[TILE_V4];       // 34,848 B
    __shared__ float4 ostg4[NCH * OP4];     //  9,216 B  (total 44,064 B -> 3 blk/CU)

    const int lane   = threadIdx.x;
    const int row    = blockIdx.y;
    const int chunk0 = blockIdx.x * NCH;

    const float* xr = x   + (size_t)row * T;
    float*       yr = out + (size_t)row * T;

    const int spanBase = chunk0 * L_CHUNK;
    int spanEnd   = spanBase + SPAN; if (spanEnd > T) spanEnd = T;
    int tileStart = spanBase - W_WARM; if (tileStart < 0) tileStart = 0;
    const int tileCount = spanEnd - tileStart;   // multiple of 4

    // ---- coalesced tile load: dense 1KB per wave-instruction ----
    for (int i = lane * 4; i < tileCount; i += 256) {
        float4 v = *(const float4*)(xr + tileStart + i);
        tile4[(i >> 2) + (i >> 7)] = v;     // +1 float4 pad per 128 samples
    }
    __syncthreads();

    const int chunk = chunk0 + lane;
    const bool alive = chunk < chunksPerRow;
    int t0 = alive ? chunk * L_CHUNK : tileStart;
    int begin = t0 - W_WARM; if (begin < tileStart) begin = tileStart;
    int end = t0 + L_CHUNK; if (end > T) end = T;
    if (!alive) { begin = tileStart; end = tileStart; }

    // direct-form I states
    float x1=0.f,x2=0.f,y1=0.f,y2=0.f;
    float u1=0.f,u2=0.f,v1=0.f,v2=0.f;
    float p1=0.f,p2=0.f,q1=0.f,q2=0.f;

    auto step = [&](float xt) -> float {
        float f = F1.b0*xt + F1.b1*x1 + F1.b2*x2;
        float y = (f - F1.a2*y2) - F1.a1*y1;
        x2 = x1; x1 = xt; y2 = y1; y1 = y;
        float u = fminf(fmaxf(y, -1.f), 1.f);

        float g = F2.b0*u + F2.b1*u1 + F2.b2*u2;
        float v = (g - F2.a2*v2) - F2.a1*v1;
        u2 = u1; u1 = u; v2 = v1; v1 = v;
        float pp = fminf(fmaxf(v, -1.f), 1.f);

        float h = F3.b0*pp + F3.b1*p1 + F3.b2*p2;
        float q = (h - F3.a2*q2) - F3.a1*q1;
        p2 = p1; p1 = pp; q2 = q1; q1 = q;
        return fminf(fmaxf(q, -1.f), 1.f);
    };

    auto ldt = [&](int t) -> float4 {       // LDS tile read, swizzle-padded
        int u = t - tileStart;
        return tile4[(u >> 2) + (u >> 7)];
    };

    // ---- warm-up (discard), 1-slot LDS prefetch ----
    float4 cur = ldt(begin);                // index 0 for dead lanes: safe
    for (int t = begin; t < t0; t += 4) {
        float4 nx = ldt(t + 4);             // t+4 <= t0 < spanEnd: in-tile
        step(cur.x); step(cur.y); step(cur.z); step(cur.w);
        cur = nx;
    }

    // ---- output pieces: compute -> LDS stage -> coalesced full-line flush ----
    for (int p = 0; p < NPIECE; ++p) {
#pragma unroll
        for (int s = 0; s < PIECE; s += 4) {
            int t = t0 + p * PIECE + s;
            if (t < end) {
                int tn = t + 4;
                float4 nx = (tn < end) ? ldt(tn) : cur;
                float o0 = step(cur.x);
                float o1 = step(cur.y);
                float o2 = step(cur.z);
                float o3 = step(cur.w);
                ostg4[lane * OP4 + (s >> 2)] = make_float4(o0, o1, o2, o3);
                cur = nx;
            }
        }
        __syncthreads();                    // staging visible
#pragma unroll
        for (int k = 0; k < 8; ++k) {       // 64 chunks x 32 floats per piece
            int i = lane * 4 + k * 256;
            int c = i >> 5;                 // chunk-in-block
            int j = i & 31;                 // dword offset (multiple of 4)
            int g = spanBase + c * L_CHUNK + p * PIECE + j;
            if (g < spanEnd) {
                *(float4*)(yr + g) = ostg4[c * OP4 + (j >> 2)];
            }
        }
        __syncthreads();                    // WAR before next piece staging
    }
}

// ---- host-side coefficient computation (double, matching numpy refs) ----

static BQ norm_ba(double b0, double b1, double b2,
                  double a0, double a1, double a2) {
    BQ r;
    r.b0 = (float)(b0/a0); r.b1 = (float)(b1/a0); r.b2 = (float)(b2/a0);
    r.a1 = (float)(a1/a0); r.a2 = (float)(a2/a0);
    return r;
}

static BQ make_eq(double f0, double gain_db, double Q) {
    const double SR = 44100.0;
    double w0 = 2.0 * M_PI * f0 / SR;
    double alpha = sin(w0) / (2.0 * Q);
    double A = pow(10.0, gain_db / 40.0);
    return norm_ba(1.0 + alpha*A, -2.0*cos(w0), 1.0 - alpha*A,
                   1.0 + alpha/A, -2.0*cos(w0), 1.0 - alpha/A);
}

static BQ make_lp(double cutoff, double Q) {
    const double SR = 44100.0;
    double w0 = 2.0 * M_PI * cutoff / SR;
    double alpha = sin(w0) / (2.0 * Q);
    double c = cos(w0);
    return norm_ba((1.0-c)/2.0, 1.0-c, (1.0-c)/2.0,
                   1.0+alpha, -2.0*c, 1.0-alpha);
}

static BQ make_hp(double cutoff, double Q) {
    const double SR = 44100.0;
    double w0 = 2.0 * M_PI * cutoff / SR;
    double alpha = sin(w0) / (2.0 * Q);
    double c = cos(w0);
    return norm_ba((1.0+c)/2.0, -(1.0+c), (1.0+c)/2.0,
                   1.0+alpha, -2.0*c, 1.0-alpha);
}

extern "C" void kernel_launch(void* const* d_in, const int* in_sizes, int n_in,
                              void* d_out, int out_size, void* d_ws, size_t ws_size,
                              hipStream_t stream) {
    const float* x = (const float*)d_in[0];
    float* out = (float*)d_out;

    const int T = 441000;
    int total = in_sizes[0];
    int B = total / T;                                  // 32

    int chunksPerRow = (T + L_CHUNK - 1) / L_CHUNK;     // 3446
    int blocksPerRow = (chunksPerRow + NCH - 1) / NCH;  // 54

    BQ f1 = make_eq(1000.0, 6.0, 1.0);
    BQ f2 = make_lp(8000.0, 0.7071067811865476);
    BQ f3 = make_hp(300.0, 0.7071067811865476);

    dim3 grid(blocksPerRow, B);
    hipLaunchKernelGGL(biquad3_kernel, grid, dim3(64), 0, stream,
                       x, out, T, chunksPerRow, f1, f2, f3);
}

// Round 5
// 145.194 us; speedup vs baseline: 1.3940x; 1.3940x over previous
//
#include <hip/hip_runtime.h>
#include <math.h>

// RandomMicEQ: cascade of 3 biquads (EQ -> LP -> HP), stage outputs clamped
// to [-1,1], recursion history UNCLAMPED (matches jax ref).
//
// Overlap-save chunking: thread = one L=64-sample chunk, run from zero state
// W=192 samples early (dominant pole r=0.9702 -> transient ~8e-4, 9x under
// the 7.7e-3 threshold; measured absmax 1.95e-3 is fp32 roundoff).
//
// R5: R4 proved LDS input staging gives ideal HBM traffic (FETCH 88->28MB)
// but its 44.5KB tile killed occupancy (3 waves/CU -> latency exposed,
// 131us). Now: L=64/W=192 -> 18KB tile, REUSED for output staging (outputs
// parked in 16 float4 regs between two cheap 1-wave syncs). 8 blocks/CU
// capacity, grid 13.5/CU -> ~2 waves/SIMD. All LDS patterns padded to lane
// dword-stride 68 == 4 mod 32 -> conflict-free b128.

struct BQ { float b0, b1, b2, a1, a2; };

#define L_CHUNK 64
#define W_WARM  192
#define NCH     64                       // chunks per block (= lanes)
#define SPAN    (NCH * L_CHUNK)          // 4096 samples output per block
#define TILE_F  (SPAN + W_WARM)          // 4288 floats max
#define TILE_V4 ((TILE_F / 64) * 17 + 1) // 67 rows * (16 data + 1 pad) + guard
#define OP4     17                       // out staging pitch (float4/chunk)

__global__ __launch_bounds__(64) void biquad3_kernel(
    const float* __restrict__ x, float* __restrict__ out,
    int T, BQ F1, BQ F2, BQ F3)
{
    __shared__ float4 lds4[TILE_V4];     // 18,256 B; tile, then out staging

    const int lane   = threadIdx.x;
    const int row    = blockIdx.y;
    const int chunk0 = blockIdx.x * NCH;

    const float* xr = x   + (size_t)row * T;
    float*       yr = out + (size_t)row * T;

    const int spanBase = chunk0 * L_CHUNK;
    int spanEnd   = spanBase + SPAN; if (spanEnd > T) spanEnd = T;
    int tileStart = spanBase - W_WARM; if (tileStart < 0) tileStart = 0;
    const int tileCount = spanEnd - tileStart;      // multiple of 4

    // ---- coalesced tile load: dense 1KB per wave-instruction ----
    for (int i = lane * 4; i < tileCount; i += 256) {
        float4 v = *(const float4*)(xr + tileStart + i);
        lds4[(i >> 2) + (i >> 6)] = v;   // +1 float4 pad per 64 floats
    }
    __syncthreads();

    const int t0 = spanBase + lane * L_CHUNK;  // may exceed T: harmless
    int begin = t0 - W_WARM; if (begin < 0) begin = 0;

    // direct-form I states for the 3 stages
    float x1=0.f,x2=0.f,y1=0.f,y2=0.f;
    float u1=0.f,u2=0.f,v1=0.f,v2=0.f;
    float p1=0.f,p2=0.f,q1=0.f,q2=0.f;

    auto step = [&](float xt) -> float {
        float f = F1.b0*xt + F1.b1*x1 + F1.b2*x2;
        float y = (f - F1.a2*y2) - F1.a1*y1;
        x2 = x1; x1 = xt; y2 = y1; y1 = y;
        float u = fminf(fmaxf(y, -1.f), 1.f);

        float g = F2.b0*u + F2.b1*u1 + F2.b2*u2;
        float v = (g - F2.a2*v2) - F2.a1*v1;
        u2 = u1; u1 = u; v2 = v1; v1 = v;
        float pp = fminf(fmaxf(v, -1.f), 1.f);

        float h = F3.b0*pp + F3.b1*p1 + F3.b2*p2;
        float q = (h - F3.a2*q2) - F3.a1*q1;
        p2 = p1; p1 = pp; q2 = q1; q1 = q;
        return fminf(fmaxf(q, -1.f), 1.f);
    };

    auto ldt = [&](int t) -> float4 {    // swizzle-padded LDS tile read
        int u = t - tileStart;
        return lds4[(u >> 2) + (u >> 6)];
    };

    // ---- warm-up (discard), 1-slot LDS prefetch ----
    float4 cur = ldt(begin);
    for (int t = begin; t < t0; t += 4) {
        float4 nx = ldt(t + 4);          // u <= lane*64+192 < tile: in-bounds
        step(cur.x); step(cur.y); step(cur.z); step(cur.w);
        cur = nx;
    }

    // ---- output: 64 samples into registers (tile LDS still live) ----
    float4 og[16];
#pragma unroll
    for (int g = 0; g < 16; ++g) {
        float4 nx = ldt(t0 + 4 * g + 4); // max idx = TILE_V4-1 (guard slot)
        og[g] = make_float4(step(cur.x), step(cur.y), step(cur.z), step(cur.w));
        cur = nx;
    }
    __syncthreads();                     // all tile reads done -> reuse LDS

    // ---- stage outputs (pitch 17 float4 -> dword stride 68 == 4 mod 32) ----
#pragma unroll
    for (int g = 0; g < 16; ++g) {
        lds4[lane * OP4 + g] = og[g];
    }
    __syncthreads();                     // staging visible

    // ---- flush: 64 chunks x 64 floats as dense 1KB wave-stores ----
#pragma unroll
    for (int k = 0; k < 16; ++k) {
        int i = lane * 4 + k * 256;      // dword offset in span
        int g = spanBase + i;
        if (g < spanEnd) {
            int c = i >> 6;              // chunk-in-block
            int j = (i & 63) >> 2;       // float4-in-chunk
            *(float4*)(yr + g) = lds4[c * OP4 + j];
        }
    }
}

// ---- host-side coefficient computation (double, matching numpy refs) ----

static BQ norm_ba(double b0, double b1, double b2,
                  double a0, double a1, double a2) {
    BQ r;
    r.b0 = (float)(b0/a0); r.b1 = (float)(b1/a0); r.b2 = (float)(b2/a0);
    r.a1 = (float)(a1/a0); r.a2 = (float)(a2/a0);
    return r;
}

static BQ make_eq(double f0, double gain_db, double Q) {
    const double SR = 44100.0;
    double w0 = 2.0 * M_PI * f0 / SR;
    double alpha = sin(w0) / (2.0 * Q);
    double A = pow(10.0, gain_db / 40.0);
    return norm_ba(1.0 + alpha*A, -2.0*cos(w0), 1.0 - alpha*A,
                   1.0 + alpha/A, -2.0*cos(w0), 1.0 - alpha/A);
}

static BQ make_lp(double cutoff, double Q) {
    const double SR = 44100.0;
    double w0 = 2.0 * M_PI * cutoff / SR;
    double alpha = sin(w0) / (2.0 * Q);
    double c = cos(w0);
    return norm_ba((1.0-c)/2.0, 1.0-c, (1.0-c)/2.0,
                   1.0+alpha, -2.0*c, 1.0-alpha);
}

static BQ make_hp(double cutoff, double Q) {
    const double SR = 44100.0;
    double w0 = 2.0 * M_PI * cutoff / SR;
    double alpha = sin(w0) / (2.0 * Q);
    double c = cos(w0);
    return norm_ba((1.0+c)/2.0, -(1.0+c), (1.0+c)/2.0,
                   1.0+alpha, -2.0*c, 1.0-alpha);
}

extern "C" void kernel_launch(void* const* d_in, const int* in_sizes, int n_in,
                              void* d_out, int out_size, void* d_ws, size_t ws_size,
                              hipStream_t stream) {
    const float* x = (const float*)d_in[0];
    float* out = (float*)d_out;

    const int T = 441000;
    int total = in_sizes[0];
    int B = total / T;                              // 32

    int blocksPerRow = (T + SPAN - 1) / SPAN;       // 108

    BQ f1 = make_eq(1000.0, 6.0, 1.0);
    BQ f2 = make_lp(8000.0, 0.7071067811865476);
    BQ f3 = make_hp(300.0, 0.7071067811865476);

    dim3 grid(blocksPerRow, B);
    hipLaunchKernelGGL(biquad3_kernel, grid, dim3(64), 0, stream,
                       x, out, T, f1, f2, f3);
}